// Round 6
// baseline (970.532 us; speedup 1.0000x reference)
//
#include <hip/hip_runtime.h>
#include <math.h>
#include <stdint.h>

// ---------------------------------------------------------------------------
// BitResidualBlock via bf16-split MFMA.
// R14: barrier-free K-loop, FIFO-corrected. R13's regression mechanism: with
// vmcnt's in-order retirement, weight loads issued AFTER staging force a full
// stage drain at first weight consumption (zero cover) — R8/R10 suffer the
// same mid-iteration drain at tap-1. Fix: per cc, issue ALL 24 weight loads
// FIRST (oldest), then stage(cc+1) (wave-private, stays in flight), then a
// counted s_waitcnt for stage(cc) — one iteration old, free. No __syncthreads
// in the K-loop (each wave stages exactly the rows it reads; halo duplicated
// at wave seams). Counted waits: issued-after-stage(cc) = 24 + NWW -> 33
// (d=1/3), 34 (d=5); last iteration 24 (no next stage; 33 would race).
// sched_barrier(0) pins weight-before-stage order + guards waits (rule #18).
// LDS 67.6/71.7/75.8 KB (d=1/3/5) -> still 2 blocks/CU. Tile, acc[8][4],
// weight path, swizzle, epilogue identical to R8/R10 (751 us verified);
// arithmetic order unchanged -> absmax must remain exactly 0.125.
// ---------------------------------------------------------------------------

constexpr int B_ = 8, C_ = 512, T_ = 4096, K_ = 3;
constexpr int WELEM = C_ * C_ * K_;  // 786432 per tensor

typedef __bf16 bf16x8 __attribute__((ext_vector_type(8)));
typedef float f32x4 __attribute__((ext_vector_type(4)));
typedef unsigned short u16x8 __attribute__((ext_vector_type(8)));

// ws byte offsets
constexpr size_t OFF_PART = 0;
constexpr size_t OFF_S = 4096;
constexpr size_t OFF_AE = 8192;
constexpr size_t OFF_IB = 16384;
constexpr size_t OFF_WQ1 = 32768;  // ushort[3*WELEM], frag-swizzled
constexpr size_t OFF_WQ2 = OFF_WQ1 + (size_t)3 * WELEM * 2;
constexpr size_t NBCT = (size_t)B_ * C_ * T_;
constexpr size_t OFF_PHI = OFF_WQ2 + (size_t)3 * WELEM * 2;  // bf16 planes
constexpr size_t OFF_PLO = OFF_PHI + NBCT * 2;
constexpr size_t OFF_QHI = OFF_PLO + NBCT * 2;
constexpr size_t OFF_QLO = OFF_QHI + NBCT * 2;
constexpr size_t OFF_ZERO = OFF_QLO + NBCT * 2;  // 4 KB zeroed region

__device__ inline unsigned short bf16_rne(float v) {
  unsigned int u = __builtin_bit_cast(unsigned int, v);
  unsigned int r = u + 0x7FFFu + ((u >> 16) & 1u);
  return (unsigned short)(r >> 16);
}

// --------------------------- absmean (deterministic) ------------------------
__global__ __launch_bounds__(256)
void absmean_partial(const float* __restrict__ w1, const float* __restrict__ w2,
                     float* __restrict__ part) {
  __shared__ float red[256];
  const int t = blockIdx.y;
  const float* src = (t < 3) ? (w1 + (size_t)t * WELEM) : (w2 + (size_t)(t - 3) * WELEM);
  const int base = blockIdx.x * (256 * 32);
  float v = 0.f;
#pragma unroll
  for (int j = 0; j < 32; ++j) v += fabsf(src[base + j * 256 + threadIdx.x]);
  red[threadIdx.x] = v;
  __syncthreads();
  for (int s = 128; s > 0; s >>= 1) {
    if (threadIdx.x < (unsigned)s) red[threadIdx.x] += red[threadIdx.x + s];
    __syncthreads();
  }
  if (threadIdx.x == 0) part[t * 96 + blockIdx.x] = red[0];
}

__global__ __launch_bounds__(128)
void absmean_final(const float* __restrict__ part, float* __restrict__ svec) {
  __shared__ float red[128];
  const int t = blockIdx.x;
  red[threadIdx.x] = (threadIdx.x < 96) ? part[t * 96 + threadIdx.x] : 0.f;
  __syncthreads();
  for (int s = 64; s > 0; s >>= 1) {
    if (threadIdx.x < (unsigned)s) red[threadIdx.x] += red[threadIdx.x + s];
    __syncthreads();
  }
  if (threadIdx.x == 0) svec[t] = red[0] / (float)WELEM;
}

// --------------------------- quantize -> ternary bf16, frag-swizzled --------
// dst layout: idx = (((st*16 + cc)*3 + tap)*32 + cot)*512 + lane*8 + j
//   where co = cot*16 + (lane&15), ci = cc*32 + (lane>>4)*8 + j.
__global__ __launch_bounds__(256)
void quantize_kernel(const float* __restrict__ src, unsigned short* __restrict__ dst,
                     const float* __restrict__ svec, int sbase) {
  const int idx = blockIdx.x * 256 + threadIdx.x;  // exact grid over 3*WELEM
  const int j = idx & 7;
  const int lane = (idx >> 3) & 63;
  const int cot = (idx >> 9) & 31;
  const int rest = idx >> 14;
  const int tap = rest % 3;
  const int rest2 = rest / 3;
  const int cc = rest2 & 15;
  const int st = rest2 >> 4;
  const int co = cot * 16 + (lane & 15);
  const int ci = cc * 32 + (lane >> 4) * 8 + j;
  const float s = svec[sbase + st];
  const float w = src[(((size_t)st * C_ + co) * C_ + ci) * K_ + tap];
  float q = rintf(w / (s + 1e-5f));
  q = fminf(1.f, fmaxf(-1.f, q));
  dst[idx] = (unsigned short)(__builtin_bit_cast(unsigned int, q) >> 16);
}

__global__ __launch_bounds__(256)
void snake_params_kernel(const float* __restrict__ al, const float* __restrict__ be,
                         float* __restrict__ ae, float* __restrict__ ib,
                         float* __restrict__ zr) {
  const int idx = blockIdx.x * 256 + threadIdx.x;
  if (idx < 3 * C_) {
    ae[idx] = expf(al[idx]);
    ib[idx] = 1.f / (expf(be[idx]) + 1e-9f);
  }
  if (idx < 1024) zr[idx] = 0.f;  // 4 KB zeros for OOB halo DMA
}

// --------------------------- transpose + hi/lo split (used once, for x) -----
__global__ __launch_bounds__(256)
void transpose_split(const float* __restrict__ X, unsigned short* __restrict__ Hi,
                     unsigned short* __restrict__ Lo) {
  __shared__ float tile[64][68];
  const int b = blockIdx.z;
  const int c0 = blockIdx.y * 64;
  const int t0 = blockIdx.x * 64;
  const int tid = threadIdx.x;
  {
    const int cl = tid >> 2, tg = tid & 3;
    const float* src = X + ((size_t)b * C_ + c0 + cl) * T_ + t0 + tg * 16;
    float4 v0 = *(const float4*)(src);
    float4 v1 = *(const float4*)(src + 4);
    float4 v2 = *(const float4*)(src + 8);
    float4 v3 = *(const float4*)(src + 12);
    float* d = &tile[cl][tg * 16];
    *(float4*)(d) = v0; *(float4*)(d + 4) = v1;
    *(float4*)(d + 8) = v2; *(float4*)(d + 12) = v3;
  }
  __syncthreads();
  {
    const int tl = tid >> 2, cg = tid & 3;
    u16x8 h0, h1, l0, l1;
#pragma unroll
    for (int j = 0; j < 16; ++j) {
      const float v = tile[cg * 16 + j][tl];
      const unsigned short hb = bf16_rne(v);
      const float hf = __builtin_bit_cast(float, (unsigned int)hb << 16);
      const unsigned short lb = bf16_rne(v - hf);
      if (j < 8) { h0[j] = hb; l0[j] = lb; }
      else       { h1[j - 8] = hb; l1[j - 8] = lb; }
    }
    const size_t off = ((size_t)b * T_ + t0 + tl) * C_ + c0 + cg * 16;
    *(u16x8*)(Hi + off) = h0; *(u16x8*)(Hi + off + 8) = h1;
    *(u16x8*)(Lo + off) = l0; *(u16x8*)(Lo + off + 8) = l1;
  }
}

// ------------------------------- MFMA conv ----------------------------------
// Block: 128 co x 256 t, 256 threads (4 waves), wave = 128 co x 64 t.
// Wave-PRIVATE double-buffered staging via global_load_lds; NO barrier in the
// K-loop. Per cc: weights (24 loads, OLDEST) -> stage(cc+1) -> counted
// vmcnt for stage(cc) -> 3 taps of ds_read+MFMA.
template <int DIL, bool SNAKE, bool PLANES, bool WF32>
__global__ __launch_bounds__(256, 2)
void conv_mfma(const unsigned short* __restrict__ Xhi,  // [b][T][C] bf16 bits
               const unsigned short* __restrict__ Xlo,
               const unsigned short* __restrict__ Wq,   // frag-swizzled
               unsigned int zoff,                       // bytes: Xhi -> zeros
               const float* __restrict__ svec,
               const float* __restrict__ bias, const float* __restrict__ aexp,
               const float* __restrict__ invb,
               const float* __restrict__ res,           // fp32 [b][co][t]
               float* __restrict__ Y,                   // fp32 [b][co][t]
               unsigned short* __restrict__ Ohi,        // [b][T][C] planes
               unsigned short* __restrict__ Olo) {
  constexpr int TT = 256;
  constexpr int RW = 64 + 2 * DIL;       // rows per wave-private buffer
  constexpr int FW = RW / 8;             // full 8-row (1 KB) DMA windows
  constexpr int REM = RW % 8;            // rows in the last partial window
  constexpr int NWW = FW + (REM ? 1 : 0);  // vmcnt issues per stage per wave
  __shared__ unsigned short Xs[2][4][RW * 64];  // [buf][wave][row*64]

  const int b = blockIdx.z;
  const int co0 = blockIdx.y * 128;
  const int cob = blockIdx.y * 8;
  const int t0 = blockIdx.x * TT;
  const int tid = threadIdx.x;
  const int lane = tid & 63;
  const int wv = tid >> 6;
  const int l15 = lane & 15;
  const int quad = lane >> 4;

  f32x4 acc[8][4] = {};

  const size_t xbase = (size_t)b * T_ * C_;
  const unsigned int plo_delta = (unsigned int)(NBCT * 2);  // bytes Xlo - Xhi
  const char* xh8 = (const char*)Xhi;

  // Per-lane DMA source byte offsets (from Xhi), one per window.
  // Wave-local LDS row rl = wnd*8 + (lane>>3); chunk c' = lane&7;
  // stored content c = c' ^ (rl&7) -> plane p = c>>2, ci-group g = c&3.
  // Global source row t = t0 + wv*64 - DIL + rl.
  unsigned int offs[NWW];
#pragma unroll
  for (int j = 0; j < NWW; ++j) {
    const int rl = j * 8 + (lane >> 3);
    const int cpr = (lane & 7) ^ (rl & 7);
    const int p = cpr >> 2, g = cpr & 3;
    const int t = t0 + wv * 64 - DIL + rl;
    unsigned int o;
    if (rl < RW && (unsigned)t < (unsigned)T_)
      o = (p ? plo_delta : 0u) + (unsigned int)((xbase + (size_t)t * C_ + g * 8) * 2);
    else
      o = zoff + (unsigned int)(g * 16);  // zeros region (advances by cc*64 <= 1 KB)
    offs[j] = o;
  }

  auto stage = [&](int cc, int buf) {
#pragma unroll
    for (int j = 0; j < NWW; ++j) {
      const char* gp = xh8 + offs[j] + cc * 64;
      auto dst = (__attribute__((address_space(3))) unsigned int*)&Xs[buf][wv][j * 512];
      if (j < FW) {
        __builtin_amdgcn_global_load_lds(
            (const __attribute__((address_space(1))) unsigned int*)gp, dst, 16, 0, 0);
      } else if ((lane >> 3) < REM) {  // partial window: masked lanes don't escape
        __builtin_amdgcn_global_load_lds(
            (const __attribute__((address_space(1))) unsigned int*)gp, dst, 16, 0, 0);
      }
    }
  };

  stage(0, 0);  // wave-private: no barrier needed anywhere in the K-loop

#pragma unroll 1
  for (int cc = 0; cc < C_ / 32; ++cc) {
    const int cur = cc & 1;

    // ---- 1) ALL weight loads for this cc, issued FIRST (oldest in queue) ---
    bf16x8 a0[8], a1[8], a2[8];
    {
      const unsigned short* wb0 =
          Wq + (((size_t)cc * K_ + 0) * 32 + cob) * 512 + (size_t)lane * 8;
      const unsigned short* wb1 =
          Wq + (((size_t)cc * K_ + 1) * 32 + cob) * 512 + (size_t)lane * 8;
      const unsigned short* wb2 =
          Wq + (((size_t)cc * K_ + 2) * 32 + cob) * 512 + (size_t)lane * 8;
#pragma unroll
      for (int m = 0; m < 8; ++m)
        a0[m] = __builtin_bit_cast(bf16x8, *(const u16x8*)(wb0 + m * 512));
#pragma unroll
      for (int m = 0; m < 8; ++m)
        a1[m] = __builtin_bit_cast(bf16x8, *(const u16x8*)(wb1 + m * 512));
#pragma unroll
      for (int m = 0; m < 8; ++m)
        a2[m] = __builtin_bit_cast(bf16x8, *(const u16x8*)(wb2 + m * 512));
    }
    __builtin_amdgcn_sched_barrier(0);  // pin: weights BEFORE staging (FIFO)

    // ---- 2) stage next tile (younger than weights -> never force-drained) --
    if (cc < C_ / 32 - 1) stage(cc + 1, 1 - cur);

    // ---- 3) counted wait: retire stage(cc) only ---------------------------
    // issued-after-stage(cc) = 24 weights + (NWW next-stage | 0 on last cc).
    if (cc < C_ / 32 - 1) {
      if constexpr (NWW == 9)  asm volatile("s_waitcnt vmcnt(33)" ::: "memory");
      else                     asm volatile("s_waitcnt vmcnt(34)" ::: "memory");
    } else {
      asm volatile("s_waitcnt vmcnt(24)" ::: "memory");
    }
    __builtin_amdgcn_sched_barrier(0);  // rule #18: no ds_read hoist above wait

    // ---- 4) 3 taps: ds_read + MFMA (weight waits are FIFO-safe) -----------
#pragma unroll
    for (int n = 0; n < 4; ++n) {
      const int r = n * 16 + l15;  // tap 0, wave-local row
      const int rw = (r & 7) * 8;
      const bf16x8 bh = __builtin_bit_cast(
          bf16x8, *(const u16x8*)&Xs[cur][wv][r * 64 + ((quad * 8) ^ rw)]);
      const bf16x8 bl = __builtin_bit_cast(
          bf16x8, *(const u16x8*)&Xs[cur][wv][r * 64 + ((quad * 8 + 32) ^ rw)]);
#pragma unroll
      for (int m = 0; m < 8; ++m) {
        acc[m][n] = __builtin_amdgcn_mfma_f32_16x16x32_bf16(a0[m], bh, acc[m][n], 0, 0, 0);
        acc[m][n] = __builtin_amdgcn_mfma_f32_16x16x32_bf16(a0[m], bl, acc[m][n], 0, 0, 0);
      }
    }
#pragma unroll
    for (int n = 0; n < 4; ++n) {
      const int r = n * 16 + l15 + DIL;
      const int rw = (r & 7) * 8;
      const bf16x8 bh = __builtin_bit_cast(
          bf16x8, *(const u16x8*)&Xs[cur][wv][r * 64 + ((quad * 8) ^ rw)]);
      const bf16x8 bl = __builtin_bit_cast(
          bf16x8, *(const u16x8*)&Xs[cur][wv][r * 64 + ((quad * 8 + 32) ^ rw)]);
#pragma unroll
      for (int m = 0; m < 8; ++m) {
        acc[m][n] = __builtin_amdgcn_mfma_f32_16x16x32_bf16(a1[m], bh, acc[m][n], 0, 0, 0);
        acc[m][n] = __builtin_amdgcn_mfma_f32_16x16x32_bf16(a1[m], bl, acc[m][n], 0, 0, 0);
      }
    }
#pragma unroll
    for (int n = 0; n < 4; ++n) {
      const int r = n * 16 + l15 + 2 * DIL;
      const int rw = (r & 7) * 8;
      const bf16x8 bh = __builtin_bit_cast(
          bf16x8, *(const u16x8*)&Xs[cur][wv][r * 64 + ((quad * 8) ^ rw)]);
      const bf16x8 bl = __builtin_bit_cast(
          bf16x8, *(const u16x8*)&Xs[cur][wv][r * 64 + ((quad * 8 + 32) ^ rw)]);
#pragma unroll
      for (int m = 0; m < 8; ++m) {
        acc[m][n] = __builtin_amdgcn_mfma_f32_16x16x32_bf16(a2[m], bh, acc[m][n], 0, 0, 0);
        acc[m][n] = __builtin_amdgcn_mfma_f32_16x16x32_bf16(a2[m], bl, acc[m][n], 0, 0, 0);
      }
    }
    // no barrier: buffers are wave-private; WAR ordered by in-wave issue order
  }

  // ---- fused epilogue ----
  const float sw = *svec;

  if (PLANES) {
    // Round-trip through LDS so plane stores are 64B-contiguous per thread.
    uint32_t* E = (uint32_t*)&Xs[0][0][0];  // 256 x 33 u32 = 33792 B (fits)
    constexpr int ELD = 33;
#pragma unroll
    for (int mb = 0; mb < 4; ++mb) {  // chunks of 2 m-tiles = 32 co
      __syncthreads();  // first iteration: all waves done with private buffers
#pragma unroll
      for (int mm = 0; mm < 2; ++mm) {
        const int m = mb * 2 + mm;
        const int cb = co0 + m * 16 + quad * 4;
        float bs[4], av[4], ibv[4];
#pragma unroll
        for (int reg = 0; reg < 4; ++reg) {
          bs[reg] = bias[cb + reg];
          if (SNAKE) { av[reg] = aexp[cb + reg]; ibv[reg] = invb[cb + reg]; }
        }
#pragma unroll
        for (int n = 0; n < 4; ++n) {
          const int tl = wv * 64 + n * 16 + l15;
          const int t = t0 + tl;
#pragma unroll
          for (int reg = 0; reg < 4; ++reg) {
            float v = sw * acc[m][n][reg] + bs[reg];
            if (SNAKE) {
              const float sn = __sinf(av[reg] * v);
              v = v + ibv[reg] * sn * sn;
            } else {
              v = v + res[((size_t)b * C_ + cb + reg) * T_ + t];
            }
            if (WF32) Y[((size_t)b * C_ + cb + reg) * T_ + t] = v;
            const unsigned short hb = bf16_rne(v);
            const float hf = __builtin_bit_cast(float, (unsigned int)hb << 16);
            const unsigned short lb = bf16_rne(v - hf);
            E[tl * ELD + mm * 16 + quad * 4 + reg] =
                ((unsigned int)hb << 16) | (unsigned int)lb;
          }
        }
      }
      __syncthreads();
      {
        const int row = tid;
        uint32_t u[32];
#pragma unroll
        for (int j = 0; j < 32; ++j) u[j] = E[row * ELD + j];
        u16x8 hq[4], lq[4];
#pragma unroll
        for (int g = 0; g < 4; ++g)
#pragma unroll
          for (int j = 0; j < 8; ++j) {
            hq[g][j] = (unsigned short)(u[g * 8 + j] >> 16);
            lq[g][j] = (unsigned short)(u[g * 8 + j] & 0xFFFFu);
          }
        const size_t poff = ((size_t)b * T_ + t0 + row) * C_ + co0 + mb * 32;
#pragma unroll
        for (int g = 0; g < 4; ++g) {
          *(u16x8*)(Ohi + poff + g * 8) = hq[g];
          *(u16x8*)(Olo + poff + g * 8) = lq[g];
        }
      }
    }
  } else {
#pragma unroll
    for (int m = 0; m < 8; ++m) {
      const int cb = co0 + m * 16 + quad * 4;
      float bs[4], av[4], ibv[4];
#pragma unroll
      for (int reg = 0; reg < 4; ++reg) {
        bs[reg] = bias[cb + reg];
        if (SNAKE) { av[reg] = aexp[cb + reg]; ibv[reg] = invb[cb + reg]; }
      }
#pragma unroll
      for (int n = 0; n < 4; ++n) {
        const int t = t0 + wv * 64 + n * 16 + l15;
#pragma unroll
        for (int reg = 0; reg < 4; ++reg) {
          float v = sw * acc[m][n][reg] + bs[reg];
          if (SNAKE) {
            const float sn = __sinf(av[reg] * v);
            v = v + ibv[reg] * sn * sn;
          } else {
            v = v + res[((size_t)b * C_ + cb + reg) * T_ + t];
          }
          Y[((size_t)b * C_ + cb + reg) * T_ + t] = v;
        }
      }
    }
  }
}

// ------------------------------- launch -------------------------------------
extern "C" void kernel_launch(void* const* d_in, const int* in_sizes, int n_in,
                              void* d_out, int out_size, void* d_ws, size_t ws_size,
                              hipStream_t stream) {
  (void)in_sizes; (void)n_in; (void)out_size; (void)ws_size;
  const float* x = (const float*)d_in[0];
  const float* w1 = (const float*)d_in[1];
  const float* b1 = (const float*)d_in[2];
  const float* al = (const float*)d_in[3];
  const float* be = (const float*)d_in[4];
  const float* w2 = (const float*)d_in[5];
  const float* b2 = (const float*)d_in[6];
  float* out = (float*)d_out;
  char* wsb = (char*)d_ws;

  float* part = (float*)(wsb + OFF_PART);
  float* svec = (float*)(wsb + OFF_S);
  float* ae = (float*)(wsb + OFF_AE);
  float* ib = (float*)(wsb + OFF_IB);
  unsigned short* wq1 = (unsigned short*)(wsb + OFF_WQ1);
  unsigned short* wq2 = (unsigned short*)(wsb + OFF_WQ2);
  unsigned short* Phi = (unsigned short*)(wsb + OFF_PHI);
  unsigned short* Plo = (unsigned short*)(wsb + OFF_PLO);
  unsigned short* Qhi = (unsigned short*)(wsb + OFF_QHI);
  unsigned short* Qlo = (unsigned short*)(wsb + OFF_QLO);
  float* zr = (float*)(wsb + OFF_ZERO);

  const unsigned int zoffP = (unsigned int)(OFF_ZERO - OFF_PHI);
  const unsigned int zoffQ = (unsigned int)(OFF_ZERO - OFF_QHI);

  absmean_partial<<<dim3(96, 6), 256, 0, stream>>>(w1, w2, part);
  absmean_final<<<6, 128, 0, stream>>>(part, svec);
  quantize_kernel<<<(3 * WELEM) / 256, 256, 0, stream>>>(w1, wq1, svec, 0);
  quantize_kernel<<<(3 * WELEM) / 256, 256, 0, stream>>>(w2, wq2, svec, 3);
  snake_params_kernel<<<6, 256, 0, stream>>>(al, be, ae, ib, zr);

  const dim3 tgrid(T_ / 64, C_ / 64, B_);
  const dim3 cgrid(T_ / 256, C_ / 128, B_);

  transpose_split<<<tgrid, 256, 0, stream>>>(x, Phi, Plo);

  // stage 0 (dil=1): conv1 P->Q planes; conv2 Q->out fp32 + P planes
  conv_mfma<1, true, true, false><<<cgrid, 256, 0, stream>>>(
      Phi, Plo, wq1 + 0 * (size_t)WELEM, zoffP, svec + 0, b1 + 0, ae + 0, ib + 0,
      nullptr, nullptr, Qhi, Qlo);
  conv_mfma<1, false, true, true><<<cgrid, 256, 0, stream>>>(
      Qhi, Qlo, wq2 + 0 * (size_t)WELEM, zoffQ, svec + 3, b2 + 0, nullptr, nullptr,
      x, out, Phi, Plo);

  // stage 1 (dil=3)
  conv_mfma<3, true, true, false><<<cgrid, 256, 0, stream>>>(
      Phi, Plo, wq1 + 1 * (size_t)WELEM, zoffP, svec + 1, b1 + C_, ae + C_, ib + C_,
      nullptr, nullptr, Qhi, Qlo);
  conv_mfma<1, false, true, true><<<cgrid, 256, 0, stream>>>(
      Qhi, Qlo, wq2 + 1 * (size_t)WELEM, zoffQ, svec + 4, b2 + C_, nullptr, nullptr,
      out, out, Phi, Plo);

  // stage 2 (dil=5): final conv2 writes fp32 only
  conv_mfma<5, true, true, false><<<cgrid, 256, 0, stream>>>(
      Phi, Plo, wq1 + 2 * (size_t)WELEM, zoffP, svec + 2, b1 + 2 * C_, ae + 2 * C_,
      ib + 2 * C_, nullptr, nullptr, Qhi, Qlo);
  conv_mfma<1, false, false, true><<<cgrid, 256, 0, stream>>>(
      Qhi, Qlo, wq2 + 2 * (size_t)WELEM, zoffQ, svec + 5, b2 + 2 * C_, nullptr, nullptr,
      out, out, nullptr, nullptr);
}

// Round 7
// 720.142 us; speedup vs baseline: 1.3477x; 1.3477x over previous
//
#include <hip/hip_runtime.h>
#include <math.h>
#include <stdint.h>

// ---------------------------------------------------------------------------
// BitResidualBlock via bf16-split MFMA.
// R15: K-loop reverted to R10 verbatim (verified best: 751 us, conv 122 us;
// all four scheduling/occupancy deviations R9/R11/R13/R14 regressed).
// Change is in the EPILOGUE TRAFFIC, the quantified remaining cost (R12
// probes: ~35 us/dispatch epi+pro, dominated by the 134 MB conv2 write
// burst): intermediate conv2 stages no longer write fp32 `out` — the next
// stage's residual is reconstructed from the hi/lo planes (hi+lo ~= v,
// rel err ~2^-16 -> absmax impact ~3e-3). Plane buffers rotate P->R->P with
// R placed in the DEAD d_out region (exactly 2 planes big); stage-2 conv2
// overwrites R with the final fp32. Saves 134 MB of writes total. Staging
// from R (a different allocation) breaks the 32-bit zoff halo trick ->
// offs[] are size_t against a passed zero-region pointer (+9 VGPR, free at
// LDS-bound 2 blocks/CU).
// ---------------------------------------------------------------------------

constexpr int B_ = 8, C_ = 512, T_ = 4096, K_ = 3;
constexpr int WELEM = C_ * C_ * K_;  // 786432 per tensor

typedef __bf16 bf16x8 __attribute__((ext_vector_type(8)));
typedef float f32x4 __attribute__((ext_vector_type(4)));
typedef unsigned short u16x8 __attribute__((ext_vector_type(8)));
typedef unsigned short u16x4 __attribute__((ext_vector_type(4)));

// ws byte offsets
constexpr size_t OFF_PART = 0;
constexpr size_t OFF_S = 4096;
constexpr size_t OFF_AE = 8192;
constexpr size_t OFF_IB = 16384;
constexpr size_t OFF_WQ1 = 32768;  // ushort[3*WELEM], frag-swizzled
constexpr size_t OFF_WQ2 = OFF_WQ1 + (size_t)3 * WELEM * 2;
constexpr size_t NBCT = (size_t)B_ * C_ * T_;
constexpr size_t OFF_PHI = OFF_WQ2 + (size_t)3 * WELEM * 2;  // bf16 planes
constexpr size_t OFF_PLO = OFF_PHI + NBCT * 2;
constexpr size_t OFF_QHI = OFF_PLO + NBCT * 2;
constexpr size_t OFF_QLO = OFF_QHI + NBCT * 2;
constexpr size_t OFF_ZERO = OFF_QLO + NBCT * 2;  // 4 KB zeroed region

__device__ inline unsigned short bf16_rne(float v) {
  unsigned int u = __builtin_bit_cast(unsigned int, v);
  unsigned int r = u + 0x7FFFu + ((u >> 16) & 1u);
  return (unsigned short)(r >> 16);
}

__device__ inline float b2f(unsigned short h) {
  return __builtin_bit_cast(float, (unsigned int)h << 16);
}

// --------------------------- absmean (deterministic) ------------------------
__global__ __launch_bounds__(256)
void absmean_partial(const float* __restrict__ w1, const float* __restrict__ w2,
                     float* __restrict__ part) {
  __shared__ float red[256];
  const int t = blockIdx.y;
  const float* src = (t < 3) ? (w1 + (size_t)t * WELEM) : (w2 + (size_t)(t - 3) * WELEM);
  const int base = blockIdx.x * (256 * 32);
  float v = 0.f;
#pragma unroll
  for (int j = 0; j < 32; ++j) v += fabsf(src[base + j * 256 + threadIdx.x]);
  red[threadIdx.x] = v;
  __syncthreads();
  for (int s = 128; s > 0; s >>= 1) {
    if (threadIdx.x < (unsigned)s) red[threadIdx.x] += red[threadIdx.x + s];
    __syncthreads();
  }
  if (threadIdx.x == 0) part[t * 96 + blockIdx.x] = red[0];
}

__global__ __launch_bounds__(128)
void absmean_final(const float* __restrict__ part, float* __restrict__ svec) {
  __shared__ float red[128];
  const int t = blockIdx.x;
  red[threadIdx.x] = (threadIdx.x < 96) ? part[t * 96 + threadIdx.x] : 0.f;
  __syncthreads();
  for (int s = 64; s > 0; s >>= 1) {
    if (threadIdx.x < (unsigned)s) red[threadIdx.x] += red[threadIdx.x + s];
    __syncthreads();
  }
  if (threadIdx.x == 0) svec[t] = red[0] / (float)WELEM;
}

// --------------------------- quantize -> ternary bf16, frag-swizzled --------
// dst layout: idx = (((st*16 + cc)*3 + tap)*32 + cot)*512 + lane*8 + j
//   where co = cot*16 + (lane&15), ci = cc*32 + (lane>>4)*8 + j.
__global__ __launch_bounds__(256)
void quantize_kernel(const float* __restrict__ src, unsigned short* __restrict__ dst,
                     const float* __restrict__ svec, int sbase) {
  const int idx = blockIdx.x * 256 + threadIdx.x;  // exact grid over 3*WELEM
  const int j = idx & 7;
  const int lane = (idx >> 3) & 63;
  const int cot = (idx >> 9) & 31;
  const int rest = idx >> 14;
  const int tap = rest % 3;
  const int rest2 = rest / 3;
  const int cc = rest2 & 15;
  const int st = rest2 >> 4;
  const int co = cot * 16 + (lane & 15);
  const int ci = cc * 32 + (lane >> 4) * 8 + j;
  const float s = svec[sbase + st];
  const float w = src[(((size_t)st * C_ + co) * C_ + ci) * K_ + tap];
  float q = rintf(w / (s + 1e-5f));
  q = fminf(1.f, fmaxf(-1.f, q));
  dst[idx] = (unsigned short)(__builtin_bit_cast(unsigned int, q) >> 16);
}

__global__ __launch_bounds__(256)
void snake_params_kernel(const float* __restrict__ al, const float* __restrict__ be,
                         float* __restrict__ ae, float* __restrict__ ib,
                         float* __restrict__ zr) {
  const int idx = blockIdx.x * 256 + threadIdx.x;
  if (idx < 3 * C_) {
    ae[idx] = expf(al[idx]);
    ib[idx] = 1.f / (expf(be[idx]) + 1e-9f);
  }
  if (idx < 1024) zr[idx] = 0.f;  // 4 KB zeros for OOB halo DMA
}

// --------------------------- transpose + hi/lo split (used once, for x) -----
__global__ __launch_bounds__(256)
void transpose_split(const float* __restrict__ X, unsigned short* __restrict__ Hi,
                     unsigned short* __restrict__ Lo) {
  __shared__ float tile[64][68];
  const int b = blockIdx.z;
  const int c0 = blockIdx.y * 64;
  const int t0 = blockIdx.x * 64;
  const int tid = threadIdx.x;
  {
    const int cl = tid >> 2, tg = tid & 3;
    const float* src = X + ((size_t)b * C_ + c0 + cl) * T_ + t0 + tg * 16;
    float4 v0 = *(const float4*)(src);
    float4 v1 = *(const float4*)(src + 4);
    float4 v2 = *(const float4*)(src + 8);
    float4 v3 = *(const float4*)(src + 12);
    float* d = &tile[cl][tg * 16];
    *(float4*)(d) = v0; *(float4*)(d + 4) = v1;
    *(float4*)(d + 8) = v2; *(float4*)(d + 12) = v3;
  }
  __syncthreads();
  {
    const int tl = tid >> 2, cg = tid & 3;
    u16x8 h0, h1, l0, l1;
#pragma unroll
    for (int j = 0; j < 16; ++j) {
      const float v = tile[cg * 16 + j][tl];
      const unsigned short hb = bf16_rne(v);
      const float hf = b2f(hb);
      const unsigned short lb = bf16_rne(v - hf);
      if (j < 8) { h0[j] = hb; l0[j] = lb; }
      else       { h1[j - 8] = hb; l1[j - 8] = lb; }
    }
    const size_t off = ((size_t)b * T_ + t0 + tl) * C_ + c0 + cg * 16;
    *(u16x8*)(Hi + off) = h0; *(u16x8*)(Hi + off + 8) = h1;
    *(u16x8*)(Lo + off) = l0; *(u16x8*)(Lo + off + 8) = l1;
  }
}

// ------------------------------- MFMA conv ----------------------------------
// Block: 128 co x 256 t, 256 threads (4 waves), wave = 128 co x 64 t.
// Async double-buffered staging via global_load_lds, one barrier per cc.
// Tap-0 weight frags software-pipelined one cc ahead (R10 structure, verified).
// RESP: residual read from hi/lo planes instead of fp32.
template <int DIL, bool SNAKE, bool PLANES, bool WF32, bool RESP>
__global__ __launch_bounds__(256, 2)
void conv_mfma(const unsigned short* __restrict__ Xhi,  // [b][T][C] bf16 bits
               const unsigned short* __restrict__ Xlo,
               const unsigned short* __restrict__ Wq,   // frag-swizzled
               const char* __restrict__ zptr,           // 4 KB zeros (halo DMA)
               const float* __restrict__ svec,
               const float* __restrict__ bias, const float* __restrict__ aexp,
               const float* __restrict__ invb,
               const unsigned short* __restrict__ reshi,  // res planes [b][T][C]
               const unsigned short* __restrict__ reslo,
               float* __restrict__ Y,                   // fp32 [b][co][t]
               unsigned short* __restrict__ Ohi,        // [b][T][C] planes
               unsigned short* __restrict__ Olo) {
  constexpr int TT = 256;
  constexpr int R = TT + 2 * DIL;
  constexpr int R8 = (R + 7) & ~7;      // rows padded to DMA window multiple
  constexpr int W8 = R8 / 8;            // 1024 B DMA windows per buffer
  constexpr int NW = (W8 + 3) / 4;      // windows per wave (ceil)
  __shared__ unsigned short Xs[2][R8 * 64];  // row = 128 B (both planes, swizzled)

  const int b = blockIdx.z;
  const int co0 = blockIdx.y * 128;
  const int cob = blockIdx.y * 8;
  const int t0 = blockIdx.x * TT;
  const int tid = threadIdx.x;
  const int lane = tid & 63;
  const int wv = tid >> 6;
  const int l15 = lane & 15;
  const int quad = lane >> 4;

  f32x4 acc[8][4] = {};

  const size_t xbase = (size_t)b * T_ * C_;
  const size_t plo_delta = NBCT * 2;  // bytes Xlo - Xhi (same in every pair)
  const char* xh8 = (const char*)Xhi;

  // Per-lane DMA source byte offsets (from Xhi), one per window handled.
  // LDS slot for lane i in window wnd: row rl = wnd*8 + (i>>3), chunk c' = i&7.
  // Stored content: c = c' ^ (rl&7) -> plane p = c>>2, ci-group g = c&3.
  // size_t offsets: halo lanes point at the ws zero region, which may live in
  // a DIFFERENT allocation than Xhi (R planes live in d_out) -> 64-bit delta.
  size_t offs[NW];
#pragma unroll
  for (int j = 0; j < NW; ++j) {
    const int wnd = wv + j * 4;
    const int rl = wnd * 8 + (lane >> 3);
    const int cpr = (lane & 7) ^ (rl & 7);
    const int p = cpr >> 2, g = cpr & 3;
    const int t = t0 - DIL + rl;
    size_t o;
    if (wnd < W8 && (unsigned)t < (unsigned)T_)
      o = (p ? plo_delta : (size_t)0) + ((xbase + (size_t)t * C_ + g * 8) * 2);
    else
      o = (size_t)(zptr + g * 16 - xh8);  // zeros (advances by cc*64 <= 1 KB)
    offs[j] = o;
  }

  auto stage = [&](int cc, int buf) {
#pragma unroll
    for (int j = 0; j < NW; ++j) {
      const int wnd = wv + j * 4;
      if (wnd < W8) {
        const char* gp = xh8 + offs[j] + cc * 64;
        __builtin_amdgcn_global_load_lds(
            (const __attribute__((address_space(1))) unsigned int*)gp,
            (__attribute__((address_space(3))) unsigned int*)&Xs[buf][wnd * 512],
            16, 0, 0);
      }
    }
  };

  stage(0, 0);

  // Prologue: tap-0 weight frags for cc=0 (rotated at the loop bottom after).
  bf16x8 a0[8];
  {
    const unsigned short* wb = Wq + ((size_t)cob) * 512 + (size_t)lane * 8;
#pragma unroll
    for (int m = 0; m < 8; ++m)
      a0[m] = __builtin_bit_cast(bf16x8, *(const u16x8*)(wb + m * 512));
  }
  __syncthreads();

#pragma unroll 1
  for (int cc = 0; cc < C_ / 32; ++cc) {
    const int cur = cc & 1;

    if (cc < C_ / 32 - 1) stage(cc + 1, 1 - cur);  // async, drains at barrier

    // ---- tap 0: a0 was prefetched last iteration -> no load-wait convoy ----
#pragma unroll
    for (int n = 0; n < 4; ++n) {
      const int r = wv * 64 + n * 16 + l15;
      const int rw = (r & 7) * 8;
      const bf16x8 bh =
          __builtin_bit_cast(bf16x8, *(const u16x8*)&Xs[cur][r * 64 + ((quad * 8) ^ rw)]);
      const bf16x8 bl =
          __builtin_bit_cast(bf16x8, *(const u16x8*)&Xs[cur][r * 64 + ((quad * 8 + 32) ^ rw)]);
#pragma unroll
      for (int m = 0; m < 8; ++m) {
        acc[m][n] = __builtin_amdgcn_mfma_f32_16x16x32_bf16(a0[m], bh, acc[m][n], 0, 0, 0);
        acc[m][n] = __builtin_amdgcn_mfma_f32_16x16x32_bf16(a0[m], bl, acc[m][n], 0, 0, 0);
      }
    }

    // ---- tap 1 ----
    bf16x8 a1[8];
    {
      const unsigned short* wb =
          Wq + (((size_t)cc * K_ + 1) * 32 + cob) * 512 + (size_t)lane * 8;
#pragma unroll
      for (int m = 0; m < 8; ++m)
        a1[m] = __builtin_bit_cast(bf16x8, *(const u16x8*)(wb + m * 512));
    }
#pragma unroll
    for (int n = 0; n < 4; ++n) {
      const int r = wv * 64 + n * 16 + l15 + DIL;
      const int rw = (r & 7) * 8;
      const bf16x8 bh =
          __builtin_bit_cast(bf16x8, *(const u16x8*)&Xs[cur][r * 64 + ((quad * 8) ^ rw)]);
      const bf16x8 bl =
          __builtin_bit_cast(bf16x8, *(const u16x8*)&Xs[cur][r * 64 + ((quad * 8 + 32) ^ rw)]);
#pragma unroll
      for (int m = 0; m < 8; ++m) {
        acc[m][n] = __builtin_amdgcn_mfma_f32_16x16x32_bf16(a1[m], bh, acc[m][n], 0, 0, 0);
        acc[m][n] = __builtin_amdgcn_mfma_f32_16x16x32_bf16(a1[m], bl, acc[m][n], 0, 0, 0);
      }
    }

    // ---- tap 2 loads, then prefetch next-cc tap 0 (L1 latency covered by
    // tap-2 MFMAs; barrier's vmcnt(0) then retires it for free), then MFMAs --
    bf16x8 a2[8];
    {
      const unsigned short* wb =
          Wq + (((size_t)cc * K_ + 2) * 32 + cob) * 512 + (size_t)lane * 8;
#pragma unroll
      for (int m = 0; m < 8; ++m)
        a2[m] = __builtin_bit_cast(bf16x8, *(const u16x8*)(wb + m * 512));
    }
    {
      const int ccn = (cc + 1) & (C_ / 32 - 1);  // wrap: in-bounds, dead value
      const unsigned short* wb =
          Wq + (((size_t)ccn * K_) * 32 + cob) * 512 + (size_t)lane * 8;
#pragma unroll
      for (int m = 0; m < 8; ++m)
        a0[m] = __builtin_bit_cast(bf16x8, *(const u16x8*)(wb + m * 512));
    }
#pragma unroll
    for (int n = 0; n < 4; ++n) {
      const int r = wv * 64 + n * 16 + l15 + 2 * DIL;
      const int rw = (r & 7) * 8;
      const bf16x8 bh =
          __builtin_bit_cast(bf16x8, *(const u16x8*)&Xs[cur][r * 64 + ((quad * 8) ^ rw)]);
      const bf16x8 bl =
          __builtin_bit_cast(bf16x8, *(const u16x8*)&Xs[cur][r * 64 + ((quad * 8 + 32) ^ rw)]);
#pragma unroll
      for (int m = 0; m < 8; ++m) {
        acc[m][n] = __builtin_amdgcn_mfma_f32_16x16x32_bf16(a2[m], bh, acc[m][n], 0, 0, 0);
        acc[m][n] = __builtin_amdgcn_mfma_f32_16x16x32_bf16(a2[m], bl, acc[m][n], 0, 0, 0);
      }
    }
    __syncthreads();  // drains staging + a0 prefetch (both had MFMA cover)
  }

  // ---- fused epilogue ----
  const float sw = *svec;

  if (PLANES) {
    // Round-trip through LDS so plane stores are 64B-contiguous per thread.
    uint32_t* E = (uint32_t*)&Xs[0][0];  // 256 x 33 u32 = 33792 B <= R8*128
    constexpr int ELD = 33;
#pragma unroll
    for (int mb = 0; mb < 4; ++mb) {  // chunks of 2 m-tiles = 32 co
      __syncthreads();
#pragma unroll
      for (int mm = 0; mm < 2; ++mm) {
        const int m = mb * 2 + mm;
        const int cb = co0 + m * 16 + quad * 4;
        float bs[4], av[4], ibv[4];
#pragma unroll
        for (int reg = 0; reg < 4; ++reg) {
          bs[reg] = bias[cb + reg];
          if (SNAKE) { av[reg] = aexp[cb + reg]; ibv[reg] = invb[cb + reg]; }
        }
#pragma unroll
        for (int n = 0; n < 4; ++n) {
          const int tl = wv * 64 + n * 16 + l15;
          const int t = t0 + tl;
          float rsum[4];
          if (RESP) {
            const size_t ra = ((size_t)b * T_ + t) * C_ + cb;
            const u16x4 rh = *(const u16x4*)(reshi + ra);
            const u16x4 rl = *(const u16x4*)(reslo + ra);
#pragma unroll
            for (int reg = 0; reg < 4; ++reg) rsum[reg] = b2f(rh[reg]) + b2f(rl[reg]);
          }
#pragma unroll
          for (int reg = 0; reg < 4; ++reg) {
            float v = sw * acc[m][n][reg] + bs[reg];
            if (SNAKE) {
              const float sn = __sinf(av[reg] * v);
              v = v + ibv[reg] * sn * sn;
            } else if (RESP) {
              v = v + rsum[reg];
            }
            if (WF32) Y[((size_t)b * C_ + cb + reg) * T_ + t] = v;
            const unsigned short hb = bf16_rne(v);
            const float hf = b2f(hb);
            const unsigned short lb = bf16_rne(v - hf);
            E[tl * ELD + mm * 16 + quad * 4 + reg] =
                ((unsigned int)hb << 16) | (unsigned int)lb;
          }
        }
      }
      __syncthreads();
      {
        const int row = tid;
        uint32_t u[32];
#pragma unroll
        for (int j = 0; j < 32; ++j) u[j] = E[row * ELD + j];
        u16x8 hq[4], lq[4];
#pragma unroll
        for (int g = 0; g < 4; ++g)
#pragma unroll
          for (int j = 0; j < 8; ++j) {
            hq[g][j] = (unsigned short)(u[g * 8 + j] >> 16);
            lq[g][j] = (unsigned short)(u[g * 8 + j] & 0xFFFFu);
          }
        const size_t poff = ((size_t)b * T_ + t0 + row) * C_ + co0 + mb * 32;
#pragma unroll
        for (int g = 0; g < 4; ++g) {
          *(u16x8*)(Ohi + poff + g * 8) = hq[g];
          *(u16x8*)(Olo + poff + g * 8) = lq[g];
        }
      }
    }
  } else {
#pragma unroll
    for (int m = 0; m < 8; ++m) {
      const int cb = co0 + m * 16 + quad * 4;
      float bs[4], av[4], ibv[4];
#pragma unroll
      for (int reg = 0; reg < 4; ++reg) {
        bs[reg] = bias[cb + reg];
        if (SNAKE) { av[reg] = aexp[cb + reg]; ibv[reg] = invb[cb + reg]; }
      }
#pragma unroll
      for (int n = 0; n < 4; ++n) {
        const int t = t0 + wv * 64 + n * 16 + l15;
        float rsum[4];
        if (RESP) {
          const size_t ra = ((size_t)b * T_ + t) * C_ + cb;
          const u16x4 rh = *(const u16x4*)(reshi + ra);
          const u16x4 rl = *(const u16x4*)(reslo + ra);
#pragma unroll
          for (int reg = 0; reg < 4; ++reg) rsum[reg] = b2f(rh[reg]) + b2f(rl[reg]);
        }
#pragma unroll
        for (int reg = 0; reg < 4; ++reg) {
          float v = sw * acc[m][n][reg] + bs[reg];
          if (SNAKE) {
            const float sn = __sinf(av[reg] * v);
            v = v + ibv[reg] * sn * sn;
          } else if (RESP) {
            v = v + rsum[reg];
          }
          Y[((size_t)b * C_ + cb + reg) * T_ + t] = v;
        }
      }
    }
  }
}

// ------------------------------- launch -------------------------------------
extern "C" void kernel_launch(void* const* d_in, const int* in_sizes, int n_in,
                              void* d_out, int out_size, void* d_ws, size_t ws_size,
                              hipStream_t stream) {
  (void)in_sizes; (void)n_in; (void)out_size; (void)ws_size;
  const float* x = (const float*)d_in[0];
  const float* w1 = (const float*)d_in[1];
  const float* b1 = (const float*)d_in[2];
  const float* al = (const float*)d_in[3];
  const float* be = (const float*)d_in[4];
  const float* w2 = (const float*)d_in[5];
  const float* b2 = (const float*)d_in[6];
  float* out = (float*)d_out;
  char* wsb = (char*)d_ws;

  float* part = (float*)(wsb + OFF_PART);
  float* svec = (float*)(wsb + OFF_S);
  float* ae = (float*)(wsb + OFF_AE);
  float* ib = (float*)(wsb + OFF_IB);
  unsigned short* wq1 = (unsigned short*)(wsb + OFF_WQ1);
  unsigned short* wq2 = (unsigned short*)(wsb + OFF_WQ2);
  unsigned short* Phi = (unsigned short*)(wsb + OFF_PHI);
  unsigned short* Plo = (unsigned short*)(wsb + OFF_PLO);
  unsigned short* Qhi = (unsigned short*)(wsb + OFF_QHI);
  unsigned short* Qlo = (unsigned short*)(wsb + OFF_QLO);
  float* zr = (float*)(wsb + OFF_ZERO);
  const char* zp = (const char*)zr;

  // R plane pair lives in the (dead until stage 2) d_out region: 2*NBCT*2B
  // = NBCT*4B = exactly out_size.
  unsigned short* Rhi = (unsigned short*)out;
  unsigned short* Rlo = (unsigned short*)out + NBCT;

  absmean_partial<<<dim3(96, 6), 256, 0, stream>>>(w1, w2, part);
  absmean_final<<<6, 128, 0, stream>>>(part, svec);
  quantize_kernel<<<(3 * WELEM) / 256, 256, 0, stream>>>(w1, wq1, svec, 0);
  quantize_kernel<<<(3 * WELEM) / 256, 256, 0, stream>>>(w2, wq2, svec, 3);
  snake_params_kernel<<<6, 256, 0, stream>>>(al, be, ae, ib, zr);

  const dim3 tgrid(T_ / 64, C_ / 64, B_);
  const dim3 cgrid(T_ / 256, C_ / 128, B_);

  transpose_split<<<tgrid, 256, 0, stream>>>(x, Phi, Plo);

  // stage 0 (dil=1): conv1 P->Q; conv2 Q (+res=P planes of x) -> R planes only
  conv_mfma<1, true, true, false, false><<<cgrid, 256, 0, stream>>>(
      Phi, Plo, wq1 + 0 * (size_t)WELEM, zp, svec + 0, b1 + 0, ae + 0, ib + 0,
      nullptr, nullptr, nullptr, Qhi, Qlo);
  conv_mfma<1, false, true, false, true><<<cgrid, 256, 0, stream>>>(
      Qhi, Qlo, wq2 + 0 * (size_t)WELEM, zp, svec + 3, b2 + 0, nullptr, nullptr,
      Phi, Plo, nullptr, Rhi, Rlo);

  // stage 1 (dil=3): conv1 R->Q; conv2 Q (+res=R planes) -> P planes only
  conv_mfma<3, true, true, false, false><<<cgrid, 256, 0, stream>>>(
      Rhi, Rlo, wq1 + 1 * (size_t)WELEM, zp, svec + 1, b1 + C_, ae + C_, ib + C_,
      nullptr, nullptr, nullptr, Qhi, Qlo);
  conv_mfma<1, false, true, false, true><<<cgrid, 256, 0, stream>>>(
      Qhi, Qlo, wq2 + 1 * (size_t)WELEM, zp, svec + 4, b2 + C_, nullptr, nullptr,
      Rhi, Rlo, nullptr, Phi, Plo);

  // stage 2 (dil=5): conv1 P->Q; conv2 Q (+res=P planes) -> fp32 out only
  // (overwrites the dead R region with the final result)
  conv_mfma<5, true, true, false, false><<<cgrid, 256, 0, stream>>>(
      Phi, Plo, wq1 + 2 * (size_t)WELEM, zp, svec + 2, b1 + 2 * C_, ae + 2 * C_,
      ib + 2 * C_, nullptr, nullptr, nullptr, Qhi, Qlo);
  conv_mfma<1, false, false, true, true><<<cgrid, 256, 0, stream>>>(
      Qhi, Qlo, wq2 + 2 * (size_t)WELEM, zp, svec + 5, b2 + 2 * C_, nullptr, nullptr,
      Phi, Plo, out, nullptr, nullptr);
}